// Round 9
// baseline (213.629 us; speedup 1.0000x reference)
//
#include <hip/hip_runtime.h>
#include <hip/hip_bf16.h>

constexpr int B = 64, N = 512, F_IN = 256, D = 128, TOPK = 20, HID = 512;

typedef __attribute__((ext_vector_type(8))) short short8_t;   // 8 bf16 = one MFMA frag
typedef __attribute__((ext_vector_type(4))) float f32x4;      // MFMA C/D frag

__device__ inline short f2bs(float f) {   // f32 -> bf16 bits (RNE)
    union { __hip_bfloat16 h; short s; } u; u.h = __float2bfloat16(f); return u.s;
}
__device__ inline float bs2f(short s) {   // bf16 bits -> f32 (shift)
    return __uint_as_float(((unsigned)(unsigned short)s) << 16);
}

// Stage whole B slab (NC rows x K cols, f32, row-major K-contig) -> LDS bf16.
// Chunked layout: chunk c (32 k's), row j at lds[c*NC*36 + j*36 + (k&31)].
// Row stride 36 shorts (72B = 18 banks): frag ds_read_b128 lands 2-way max (free).
template<int NC, int K>
__device__ inline void stageB(short* lds_b, const float* __restrict__ src, int t) {
    constexpr int G = 256 / NC;      // thread groups over K
    constexpr int GK = K / G;        // k's per thread
    int j = t & (NC - 1), g = t / NC;
    const float* p = src + (size_t)j * K + g * GK;
    #pragma unroll
    for (int kk = 0; kk < GK; kk += 8) {
        float4 x = *(const float4*)(p + kk);
        float4 y = *(const float4*)(p + kk + 4);
        short8_t v = { f2bs(x.x), f2bs(x.y), f2bs(x.z), f2bs(x.w),
                       f2bs(y.x), f2bs(y.y), f2bs(y.z), f2bs(y.w) };
        int kg = g * GK + kk;
        *(short8_t*)&lds_b[(kg >> 5) * (NC * 36) + j * 36 + (kg & 31)] = v;
    }
}

// ---------------- K0: row norms + att_em dots + emb passthrough copy ----------------
__global__ void k_norm(const float* __restrict__ W, const float* __restrict__ aei,
                       const float* __restrict__ aej, float* __restrict__ inv_norm,
                       float* __restrict__ ei, float* __restrict__ ej,
                       float* __restrict__ out_emb) {
    int n = blockIdx.x, t = threadIdx.x;  // 128 threads
    float w = W[n * D + t];
    out_emb[n * D + t] = w;
    float s0 = w * w, s1 = w * aei[t], s2 = w * aej[t];
    #pragma unroll
    for (int o = 32; o > 0; o >>= 1) {
        s0 += __shfl_down(s0, o); s1 += __shfl_down(s1, o); s2 += __shfl_down(s2, o);
    }
    __shared__ float r[6];
    if ((t & 63) == 0) { int q = t >> 6; r[q * 3] = s0; r[q * 3 + 1] = s1; r[q * 3 + 2] = s2; }
    __syncthreads();
    if (t == 0) {
        inv_norm[n] = 1.0f / sqrtf(r[0] + r[3]);
        ei[n] = r[1] + r[4];
        ej[n] = r[2] + r[5];
    }
}

// ---------------- K1a: cos tile 32x32, grid 16x16=256 blocks ----------------
__global__ __launch_bounds__(256) void k_cos(const float* __restrict__ W,
                                             const float* __restrict__ inv_norm,
                                             float* __restrict__ cosm) {
    __shared__ float la[32][33];
    __shared__ float lb[32][33];
    int j0 = blockIdx.x * 32, i0 = blockIdx.y * 32, t = threadIdx.x;
    int ix = (t & 15) * 2, jx = (t >> 4) * 2;
    float acc[2][2] = {};
    for (int k0 = 0; k0 < D; k0 += 32) {
        #pragma unroll
        for (int i = 0; i < 4; ++i) {
            int lin = t + i * 256, rl = lin & 31, kk = lin >> 5;
            la[kk][rl] = W[(size_t)(i0 + rl) * D + k0 + kk];
            lb[kk][rl] = W[(size_t)(j0 + rl) * D + k0 + kk];
        }
        __syncthreads();
        #pragma unroll
        for (int kk = 0; kk < 32; ++kk) {
            float a0 = la[kk][ix], a1 = la[kk][ix + 1];
            float b0 = lb[kk][jx], b1 = lb[kk][jx + 1];
            acc[0][0] += a0 * b0; acc[0][1] += a0 * b1;
            acc[1][0] += a1 * b0; acc[1][1] += a1 * b1;
        }
        __syncthreads();
    }
    #pragma unroll
    for (int ii = 0; ii < 2; ++ii) {
        float inv_i = inv_norm[i0 + ix + ii];
        float2 v;
        v.x = acc[ii][0] * inv_i * inv_norm[j0 + jx + 0];
        v.y = acc[ii][1] * inv_i * inv_norm[j0 + jx + 1];
        *(float2*)&cosm[(size_t)(i0 + ix + ii) * N + j0 + jx] = v;
    }
}

// ---------------- K1b: top-20 selection, wave-per-row ----------------
__global__ __launch_bounds__(256) void k_sel(const float* __restrict__ cosm,
                                             int* __restrict__ topk,
                                             float* __restrict__ out_idx) {
    int t = threadIdx.x, wid = t >> 6, lane = t & 63;
    int i = blockIdx.x * 4 + wid;
    float4 p0 = *(const float4*)&cosm[(size_t)i * N + lane * 8];
    float4 p1 = *(const float4*)&cosm[(size_t)i * N + lane * 8 + 4];
    float v[8] = {p0.x, p0.y, p0.z, p0.w, p1.x, p1.y, p1.z, p1.w};
    for (int k = 0; k < TOPK; ++k) {
        float bv = v[0]; int bc = 0;
        #pragma unroll
        for (int c = 1; c < 8; ++c) if (v[c] > bv) { bv = v[c]; bc = c; }
        int bj = lane * 8 + bc;
        #pragma unroll
        for (int o = 1; o < 64; o <<= 1) {
            float ov = __shfl_xor(bv, o);
            int  oj = __shfl_xor(bj, o);
            if (ov > bv || (ov == bv && oj < bj)) { bv = ov; bj = oj; }
        }
        if (lane == 0) {
            topk[i * TOPK + k] = bj;
            out_idx[i * TOPK + k] = (float)bj;
        }
        int oc = bj & 7; bool owner = (bj >> 3) == lane;
        #pragma unroll
        for (int c = 0; c < 8; ++c) if (owner && c == oc) v[c] = -INFINITY;
    }
}

// ---------------- xl: barrier-free K-loop, fused transpose-by-gather + scores ---------
// Block: 64 nodes x 128 d; 4 waves x 16 nodes. B slab (lin_w, 72KB bf16) staged once.
// A frags read directly from data[b][f][n]: lane index = node -> coalesced per f.
__global__ __launch_bounds__(256) void k_xl(const float* __restrict__ data,
                                            const float* __restrict__ lin_w,
                                            const float* __restrict__ att_i,
                                            const float* __restrict__ att_j,
                                            const float* __restrict__ ei,
                                            const float* __restrict__ ej,
                                            short* __restrict__ xlb,
                                            float* __restrict__ s_i,
                                            float* __restrict__ s_j) {
    __shared__ __align__(16) short lds_b[8 * 128 * 36];   // 72 KB
    int n0 = blockIdx.x * 64, b = blockIdx.y, t = threadIdx.x;
    int wid = t >> 6, lane = t & 63;
    int wm = wid * 16, lr = lane & 15, quad = lane >> 4;
    stageB<128, 256>(lds_b, lin_w, t);
    __syncthreads();
    f32x4 acc[8] = {};
    int arow = n0 + wm + lr;
    #pragma unroll
    for (int c = 0; c < 8; ++c) {
        const float* ap = data + ((size_t)b * F_IN + c * 32 + quad * 8) * N + arow;
        short8_t a;
        #pragma unroll
        for (int j = 0; j < 8; ++j) a[j] = f2bs(ap[(size_t)j * N]);
        const short* bp = lds_b + c * (128 * 36) + lr * 36 + quad * 8;
        #pragma unroll
        for (int ns = 0; ns < 8; ++ns) {
            short8_t bfr = *(const short8_t*)(bp + ns * 16 * 36);
            acc[ns] = __builtin_amdgcn_mfma_f32_16x16x32_bf16(a, bfr, acc[ns], 0, 0, 0);
        }
    }
    // store xl (bf16)
    #pragma unroll
    for (int ns = 0; ns < 8; ++ns) {
        int col = ns * 16 + lr;
        #pragma unroll
        for (int r = 0; r < 4; ++r)
            xlb[((size_t)b * N + n0 + wm + quad * 4 + r) * D + col] = f2bs(acc[ns][r]);
    }
    // fused attention scores (rows fully within wave now)
    #pragma unroll
    for (int r = 0; r < 4; ++r) {
        float si = 0.f, sj = 0.f;
        #pragma unroll
        for (int ns = 0; ns < 8; ++ns) {
            int col = ns * 16 + lr;
            float x = acc[ns][r];
            si += x * att_i[col];
            sj += x * att_j[col];
        }
        #pragma unroll
        for (int o = 1; o < 16; o <<= 1) { si += __shfl_xor(si, o); sj += __shfl_xor(sj, o); }
        if (lr == 0) {
            int n = n0 + wm + quad * 4 + r;
            s_i[b * N + n] = si + ei[n];
            s_j[b * N + n] = sj + ej[n];
        }
    }
}

// ---------------- K4: softmax(20) + aggregate + BN/ReLU/gate -> Gt[b][d][n] bf16 -----
__global__ __launch_bounds__(256) void k_attn2(const short* __restrict__ xlb,
                                               const float* __restrict__ emb,
                                               const int* __restrict__ topk,
                                               const float* __restrict__ s_i,
                                               const float* __restrict__ s_j,
                                               const float* __restrict__ gnn_bias,
                                               const float* __restrict__ bn_gamma,
                                               const float* __restrict__ bn_beta,
                                               short* __restrict__ Gt) {
    __shared__ float alph[16][20];
    __shared__ int   js[16][20];
    __shared__ float lt[16][129];
    int n0 = blockIdx.x * 16, b = blockIdx.y, t = threadIdx.x;
    for (int e = t; e < 16 * TOPK; e += 256) {
        int nl = e / TOPK, k = e - nl * TOPK;
        int j = topk[(n0 + nl) * TOPK + k];
        js[nl][k] = j;
        float al = s_i[b * N + n0 + nl] + s_j[b * N + j];
        alph[nl][k] = al >= 0.f ? al : 0.2f * al;
    }
    __syncthreads();
    if (t < 16) {
        float m = -INFINITY;
        for (int k = 0; k < TOPK; ++k) m = fmaxf(m, alph[t][k]);
        float s = 0.f;
        for (int k = 0; k < TOPK; ++k) { float e_ = expf(alph[t][k] - m); alph[t][k] = e_; s += e_; }
        float inv = 1.0f / s;
        for (int k = 0; k < TOPK; ++k) alph[t][k] *= inv;
    }
    __syncthreads();
    {
        int nl = t >> 4, dl = (t & 15) * 8;
        float a[8] = {};
        for (int k = 0; k < TOPK; ++k) {
            float w = alph[nl][k];
            short8_t xv = *(const short8_t*)&xlb[((size_t)b * N + js[nl][k]) * D + dl];
            #pragma unroll
            for (int c = 0; c < 8; ++c) a[c] += w * bs2f(xv[c]);
        }
        const float bnk = 0.9999950000374997f;  // 1/sqrt(1+1e-5)
        #pragma unroll
        for (int c = 0; c < 8; ++c) {
            int d = dl + c;
            float h = (a[c] + gnn_bias[d]) * (bn_gamma[d] * bnk) + bn_beta[d];
            h = fmaxf(h, 0.f);
            lt[nl][d] = h * emb[(n0 + nl) * D + d];
        }
    }
    __syncthreads();
    {
        int d = t >> 1, half = t & 1;
        short8_t v;
        #pragma unroll
        for (int j = 0; j < 8; ++j) v[j] = f2bs(lt[half * 8 + j][d]);
        *(short8_t*)&Gt[((size_t)b * D + d) * N + n0 + half * 8] = v;
    }
}

// ---------------- gemm1: barrier-free. Block 128d x 64h, grid (8, 64) ----------------
__global__ __launch_bounds__(256) void k_gemm1(const short* __restrict__ Gt,
                                               const float* __restrict__ w1,
                                               short* __restrict__ out1) {
    __shared__ __align__(16) short lds_b[16 * 64 * 36];   // 72 KB
    int h0 = blockIdx.x * 64, b = blockIdx.y, t = threadIdx.x;
    int wid = t >> 6, lane = t & 63;
    int wm = wid * 32, lr = lane & 15, quad = lane >> 4;
    stageB<64, 512>(lds_b, w1 + (size_t)h0 * N, t);
    __syncthreads();
    f32x4 acc[2][4] = {};
    const short* A = Gt + (size_t)b * D * N;
    #pragma unroll
    for (int c = 0; c < 16; ++c) {
        short8_t a[2];
        #pragma unroll
        for (int ms = 0; ms < 2; ++ms)
            a[ms] = *(const short8_t*)&A[(size_t)(wm + ms * 16 + lr) * N + c * 32 + quad * 8];
        const short* bp = lds_b + c * (64 * 36) + lr * 36 + quad * 8;
        #pragma unroll
        for (int ns = 0; ns < 4; ++ns) {
            short8_t bfr = *(const short8_t*)(bp + ns * 16 * 36);
            #pragma unroll
            for (int ms = 0; ms < 2; ++ms)
                acc[ms][ns] = __builtin_amdgcn_mfma_f32_16x16x32_bf16(a[ms], bfr, acc[ms][ns], 0, 0, 0);
        }
    }
    #pragma unroll
    for (int ms = 0; ms < 2; ++ms)
        #pragma unroll
        for (int ns = 0; ns < 4; ++ns) {
            int mb = wm + ms * 16 + quad * 4, col = h0 + ns * 16 + lr;
            #pragma unroll
            for (int r = 0; r < 4; ++r)
                out1[((size_t)b * D + mb + r) * HID + col] = f2bs(acc[ms][ns][r]);
        }
}

// ---------------- gemm2: barrier-free. Block 128d x 64h, grid (8, 64) ----------------
__global__ __launch_bounds__(256) void k_gemm2(const short* __restrict__ out1,
                                               const float* __restrict__ w2,
                                               const float* __restrict__ b2,
                                               float* __restrict__ out) {
    __shared__ __align__(16) short lds_b[16 * 64 * 36];   // 72 KB
    int h0 = blockIdx.x * 64, b = blockIdx.y, t = threadIdx.x;
    int wid = t >> 6, lane = t & 63;
    int wm = wid * 32, lr = lane & 15, quad = lane >> 4;
    stageB<64, 512>(lds_b, w2 + (size_t)h0 * HID, t);
    __syncthreads();
    f32x4 acc[2][4] = {};
    const short* A = out1 + (size_t)b * D * HID;
    #pragma unroll
    for (int c = 0; c < 16; ++c) {
        short8_t a[2];
        #pragma unroll
        for (int ms = 0; ms < 2; ++ms)
            a[ms] = *(const short8_t*)&A[(size_t)(wm + ms * 16 + lr) * HID + c * 32 + quad * 8];
        const short* bp = lds_b + c * (64 * 36) + lr * 36 + quad * 8;
        #pragma unroll
        for (int ns = 0; ns < 4; ++ns) {
            short8_t bfr = *(const short8_t*)(bp + ns * 16 * 36);
            #pragma unroll
            for (int ms = 0; ms < 2; ++ms)
                acc[ms][ns] = __builtin_amdgcn_mfma_f32_16x16x32_bf16(a[ms], bfr, acc[ms][ns], 0, 0, 0);
        }
    }
    #pragma unroll
    for (int ms = 0; ms < 2; ++ms)
        #pragma unroll
        for (int ns = 0; ns < 4; ++ns) {
            int mb = wm + ms * 16 + quad * 4, col = h0 + ns * 16 + lr;
            float bias = b2[col];
            #pragma unroll
            for (int r = 0; r < 4; ++r)
                out[((size_t)b * D + mb + r) * HID + col] =
                    1.0f / (1.0f + expf(-(acc[ms][ns][r] + bias)));
        }
}

extern "C" void kernel_launch(void* const* d_in, const int* in_sizes, int n_in,
                              void* d_out, int out_size, void* d_ws, size_t ws_size,
                              hipStream_t stream) {
    const float* data     = (const float*)d_in[0];
    const float* emb      = (const float*)d_in[1];
    const float* lin_w    = (const float*)d_in[2];
    const float* att_i    = (const float*)d_in[3];
    const float* att_j    = (const float*)d_in[4];
    const float* att_em_i = (const float*)d_in[5];
    const float* att_em_j = (const float*)d_in[6];
    const float* gnn_bias = (const float*)d_in[7];
    const float* bn_gamma = (const float*)d_in[8];
    const float* bn_beta  = (const float*)d_in[9];
    const float* w1       = (const float*)d_in[10];
    const float* w2       = (const float*)d_in[11];
    const float* b2       = (const float*)d_in[12];
    float* out            = (float*)d_out;   // f32 outputs: [out | emb | topk_idx]

    float* ws       = (float*)d_ws;
    float* inv_norm = ws;                                  // 512 f32
    float* ei       = ws + 512;                            // 512 f32
    float* ej       = ws + 1024;                           // 512 f32
    int*   topk     = (int*)(ws + 1536);                   // 10240 i32
    float* s_i      = ws + 1536 + N * TOPK;                // 32768 f32
    float* s_j      = s_i + B * N;                         // 32768 f32
    short* S        = (short*)(ws + 77312);                // 24 MB region (16B aligned)
    short* Gt       = S;                                   // B*D*N bf16 = 8 MB
    short* out1     = S + (size_t)B * D * N;               // 8 MB
    short* xlb      = S + 2 * (size_t)B * D * N;           // 8 MB
    float* cosm     = (float*)S;                           // 1 MB, dead before attn2 writes Gt

    float* out_emb = out + (size_t)B * D * HID;
    float* out_idx = out_emb + (size_t)N * D;

    hipLaunchKernelGGL(k_norm,  dim3(N),              dim3(D),   0, stream, emb, att_em_i, att_em_j, inv_norm, ei, ej, out_emb);
    hipLaunchKernelGGL(k_cos,   dim3(N / 32, N / 32), dim3(256), 0, stream, emb, inv_norm, cosm);
    hipLaunchKernelGGL(k_sel,   dim3(N / 4),          dim3(256), 0, stream, cosm, topk, out_idx);
    hipLaunchKernelGGL(k_xl,    dim3(N / 64, B),      dim3(256), 0, stream, data, lin_w, att_i, att_j, ei, ej, xlb, s_i, s_j);
    hipLaunchKernelGGL(k_attn2, dim3(N / 16, B),      dim3(256), 0, stream, xlb, emb, topk, s_i, s_j, gnn_bias, bn_gamma, bn_beta, Gt);
    hipLaunchKernelGGL(k_gemm1, dim3(HID / 64, B),    dim3(256), 0, stream, Gt, w1, out1);
    hipLaunchKernelGGL(k_gemm2, dim3(HID / 64, B),    dim3(256), 0, stream, out1, w2, b2, out);
}